// Round 13
// baseline (1279.175 us; speedup 1.0000x reference)
//
#include <hip/hip_runtime.h>
#include <hip/hip_bf16.h>

#define NN 100000
#define EE 300000
#define GG 4000
#define LL 5
#define GPB 4
#define SC_CHUNK 1024
#define SC_NB ((NN + SC_CHUNK - 1) / SC_CHUNK)   // 98

typedef _Float16 half8  __attribute__((ext_vector_type(8)));
typedef _Float16 half4v __attribute__((ext_vector_type(4)));
typedef float    f32x4  __attribute__((ext_vector_type(4)));

__device__ inline short f2h(float f) {
    _Float16 h = (_Float16)f;
    short s; __builtin_memcpy(&s, &h, 2); return s;
}

__device__ inline void async_load16(const void* g, void* l) {
    __builtin_amdgcn_global_load_lds(
        (const __attribute__((address_space(1))) unsigned int*)g,
        (__attribute__((address_space(3))) unsigned int*)l, 16, 0, 0);
}

// ---------------- CSR build ----------------
__global__ __launch_bounds__(256) void k_count(
    int* __restrict__ deg, const int* __restrict__ ei)
{
    int e = blockIdx.x * 256 + threadIdx.x;
    if (e < EE) atomicAdd(&deg[ei[EE + e]], 1);
}

__global__ __launch_bounds__(256) void k_scan_partial(
    int* __restrict__ partial, const int* __restrict__ deg)
{
    int b = blockIdx.x, t = threadIdx.x;
    int lane = t & 63, w = t >> 6;
    int base = b * SC_CHUNK + t * 4;
    int s = 0;
#pragma unroll
    for (int j = 0; j < 4; ++j) {
        int i = base + j;
        if (i < NN) s += deg[i];
    }
#pragma unroll
    for (int off = 1; off < 64; off <<= 1) s += __shfl_xor(s, off, 64);
    __shared__ int ws[4];
    if (lane == 0) ws[w] = s;
    __syncthreads();
    if (t == 0) partial[b] = ws[0] + ws[1] + ws[2] + ws[3];
}

__global__ __launch_bounds__(128) void k_scan_base(
    int* __restrict__ bases, int* __restrict__ offs, const int* __restrict__ partial)
{
    int t = threadIdx.x;
    int lane = t & 63, w = t >> 6;
    int p = (t < SC_NB) ? partial[t] : 0;
    int x = p;
#pragma unroll
    for (int off = 1; off < 64; off <<= 1) {
        int nb = __shfl_up(x, off, 64);
        if (lane >= off) x += nb;
    }
    __shared__ int w0tot;
    if (t == 63) w0tot = x;
    __syncthreads();
    if (w == 1) x += w0tot;
    if (t < SC_NB) bases[t] = x - p;
    if (t == 0) offs[NN] = EE;
}

__global__ __launch_bounds__(256) void k_scan_final(
    int* __restrict__ offs, int* __restrict__ cursor,
    const int* __restrict__ deg, const int* __restrict__ bases)
{
    int b = blockIdx.x, t = threadIdx.x;
    int lane = t & 63, w = t >> 6;
    int base = b * SC_CHUNK + t * 4;
    int v[4], pre[4], run = 0;
#pragma unroll
    for (int j = 0; j < 4; ++j) {
        int i = base + j;
        v[j] = (i < NN) ? deg[i] : 0;
        pre[j] = run;
        run += v[j];
    }
    int x = run;
#pragma unroll
    for (int off = 1; off < 64; off <<= 1) {
        int nb = __shfl_up(x, off, 64);
        if (lane >= off) x += nb;
    }
    int tex = x - run;
    __shared__ int ws[4];
    if (lane == 63) ws[w] = x;
    __syncthreads();
    int woff = 0;
    for (int k = 0; k < 4; ++k) if (k < w) woff += ws[k];
    int tbase = bases[b] + woff + tex;
#pragma unroll
    for (int j = 0; j < 4; ++j) {
        int i = base + j;
        if (i < NN) { offs[i] = tbase + pre[j]; cursor[i] = tbase + pre[j]; }
    }
}

__global__ __launch_bounds__(256) void k_fill(
    int* __restrict__ csr, int* __restrict__ cursor,
    const int* __restrict__ ei, const int* __restrict__ ea)
{
    int e = blockIdx.x * 256 + threadIdx.x;
    if (e >= EE) return;
    int s = ei[e];
    int d = ei[EE + e];
    int c = ea[2 * e] * 3 + ea[2 * e + 1];
    int slot = atomicAdd(&cursor[d], 1);
    csr[slot] = s | (c << 20);
}

// ---------------- graph offsets ----------------
__global__ __launch_bounds__(256) void k_goffs(
    int* __restrict__ goffs, const int* __restrict__ batch)
{
    int n = blockIdx.x * 256 + threadIdx.x;
    if (n >= NN) return;
    int b = batch[n];
    int bp = (n == 0) ? -1 : batch[n - 1];
    for (int g = bp + 1; g <= b; ++g) goffs[g] = n;
    if (n == NN - 1)
        for (int g = b + 1; g <= GG; ++g) goffs[g] = NN;
}

// ---------------- combo tables ----------------
__global__ __launch_bounds__(256) void k_combo(
    float* __restrict__ tbl, const float* __restrict__ ee1, const float* __restrict__ ee2)
{
    int c = blockIdx.x;
    int l = blockIdx.y;
    int t = threadIdx.x;
    int i1 = (c < 9) ? c / 3 : 4;
    int i2 = (c < 9) ? c % 3 : 0;
    tbl[((size_t)l * 10 + c) * 256 + t] =
        ee1[((size_t)l * 6 + i1) * 256 + t] + ee2[((size_t)l * 3 + i2) * 256 + t];
}

// ---------------- embW pack (fully parallel) ----------------
__global__ __launch_bounds__(256) void k_pack_emb(
    _Float16* __restrict__ Wep, const float* __restrict__ embW)
{
    int idx = blockIdx.x * 256 + threadIdx.x;   // 16384 total
    int ks = idx >> 13, r = idx & 8191;
    int n = r >> 5, kk = r & 31;
    int k = ks * 32 + kk;
    float v = (k < 40) ? embW[(size_t)k * 256 + n] : 0.f;
    Wep[idx] = (_Float16)v;
}

// ---------------- embed via MFMA ----------------
__global__ __launch_bounds__(256) void k_embed_mfma(
    _Float16* __restrict__ H, const float* __restrict__ x,
    const _Float16* __restrict__ Wep, const float* __restrict__ bias)
{
    __shared__ __align__(16) char smem[67584];
    _Float16* As = (_Float16*)smem;
    _Float16* Bs = (_Float16*)(smem + 16384);
    _Float16* Cs = (_Float16*)smem;

    const int t = threadIdx.x;
    const int w = t >> 6, lane = t & 63;
    const int quad = lane >> 4, l16 = lane & 15;
    const int wr = w >> 1, wc = w & 1;
    const int gm0 = blockIdx.x * 128;

#pragma unroll
    for (int i = 0; i < 8; ++i) {
        int u = i * 256 + t;
        async_load16((const char*)Wep + u * 16, (char*)Bs + u * 16);
    }

    {
        int row = t >> 1, half = t & 1;
        int rg = gm0 + row; if (rg > NN - 1) rg = NN - 1;
        const float* xp = x + (size_t)rg * 40 + half * 20;
        float v[20];
#pragma unroll
        for (int j = 0; j < 5; ++j) {
            float4 q = *(const float4*)(xp + j * 4);
            v[j * 4 + 0] = q.x; v[j * 4 + 1] = q.y; v[j * 4 + 2] = q.z; v[j * 4 + 3] = q.w;
        }
#pragma unroll
        for (int j = 0; j < 20; ++j) {
            int col = half * 20 + j;
            int ks = col >> 5, kk = col & 31;
            As[ks * 4096 + row * 32 + kk] = (_Float16)v[j];
        }
        int kb = 8 + half * 12;
#pragma unroll
        for (int j = 0; j < 12; ++j)
            As[4096 + row * 32 + kb + j] = (_Float16)0.f;
    }

    float biasreg[8];
#pragma unroll
    for (int nt = 0; nt < 8; ++nt)
        biasreg[nt] = bias[wc * 128 + nt * 16 + l16];

    f32x4 acc[4][8];
#pragma unroll
    for (int i = 0; i < 4; ++i)
#pragma unroll
        for (int j = 0; j < 8; ++j) acc[i][j] = (f32x4){0.f, 0.f, 0.f, 0.f};

    __syncthreads();

#pragma unroll
    for (int ks = 0; ks < 2; ++ks) {
        half8 af[4], bfr[8];
#pragma unroll
        for (int mt = 0; mt < 4; ++mt)
            af[mt] = *(const half8*)(As + ks * 4096 + (wr * 64 + mt * 16 + l16) * 32 + quad * 8);
#pragma unroll
        for (int nt = 0; nt < 8; ++nt)
            bfr[nt] = *(const half8*)(Bs + ks * 8192 + (wc * 128 + nt * 16 + l16) * 32 + quad * 8);
#pragma unroll
        for (int mt = 0; mt < 4; ++mt)
#pragma unroll
            for (int nt = 0; nt < 8; ++nt)
                acc[mt][nt] = __builtin_amdgcn_mfma_f32_16x16x32_f16(
                    af[mt], bfr[nt], acc[mt][nt], 0, 0, 0);
    }

    __syncthreads();
#pragma unroll
    for (int mt = 0; mt < 4; ++mt)
#pragma unroll
        for (int nt = 0; nt < 8; ++nt)
#pragma unroll
            for (int r = 0; r < 4; ++r) {
                int row = wr * 64 + mt * 16 + quad * 4 + r;
                int col = wc * 128 + nt * 16 + l16;
                Cs[row * 264 + col] = (_Float16)fmaxf(acc[mt][nt][r] + biasreg[nt], 0.f);
            }
    __syncthreads();
#pragma unroll
    for (int i = 0; i < 16; ++i) {
        int u = i * 256 + t;
        int m = u >> 5, ch = u & 31;
        int grow = gm0 + m;
        if (grow < NN)
            *(int4*)(H + (size_t)grow * 256 + ch * 8) =
                *(const int4*)(Cs + m * 264 + ch * 8);
    }
}

// ---------------- fused aggregate (AFF=0: identity affine, layer 0) -------
template <int AFF>
__global__ __launch_bounds__(256) void k_aggregate(
    _Float16* __restrict__ agg, const _Float16* __restrict__ hin,
    const int* __restrict__ offs, const int* __restrict__ csr,
    const float* __restrict__ tbl,
    const float* __restrict__ scale, const float* __restrict__ shift)
{
    int t = threadIdx.x;
    int w = t >> 6, lane = t & 63;
    int n = blockIdx.x * 4 + w;

    f32x4 sc, sh;
    if (AFF) { sc = ((const f32x4*)scale)[lane]; sh = ((const f32x4*)shift)[lane]; }
    const f32x4* tb4 = (const f32x4*)tbl;

    half4v hv = *(const half4v*)(hin + (size_t)n * 256 + lane * 4);
    f32x4 acc = tb4[9 * 64 + lane];
#pragma unroll
    for (int i = 0; i < 4; ++i) {
        float v = (float)hv[i];
        if (AFF) v = fmaf(v, sc[i], sh[i]);
        acc[i] += fmaxf(v, 0.f);
    }

    int o0 = offs[n], o1 = offs[n + 1];
    for (int j = o0; j < o1; ++j) {
        int entry = csr[j];
        int s = entry & 0xFFFFF;
        int c = entry >> 20;
        half4v gv = *(const half4v*)(hin + (size_t)s * 256 + lane * 4);
        f32x4 tv = tb4[c * 64 + lane];
#pragma unroll
        for (int i = 0; i < 4; ++i) {
            float v = (float)gv[i];
            if (AFF) v = fmaf(v, sc[i], sh[i]);
            acc[i] += fmaxf(v, 0.f) + tv[i];
        }
    }

    half4v o;
#pragma unroll
    for (int i = 0; i < 4; ++i) o[i] = (_Float16)acc[i];
    *(half4v*)(agg + (size_t)n * 256 + lane * 4) = o;
}

// ---------------- weight pack ----------------
__global__ __launch_bounds__(256) void k_pack(
    short* __restrict__ dst, const float* __restrict__ src, int K, int Nsz)
{
    int nb = blockIdx.x, kb = blockIdx.y, l = blockIdx.z;
    int t = threadIdx.x;
    __shared__ float T[32][65];
    const float* s = src + ((size_t)l * K + kb * 32) * Nsz + nb * 64;
#pragma unroll
    for (int i = 0; i < 8; ++i) {
        int idx = i * 256 + t;
        int kk = idx >> 6, nl = idx & 63;
        T[kk][nl] = s[(size_t)kk * Nsz + nl];
    }
    __syncthreads();
    int nl = t >> 2, kq = t & 3;
    union { short s[8]; int4 v; } o;
#pragma unroll
    for (int j = 0; j < 8; ++j) o.s[j] = f2h(T[kq * 8 + j][nl]);
    short* d = dst + (((size_t)l * (K / 32) + kb) * Nsz + nb * 64 + nl) * 32 + kq * 8;
    *(int4*)d = o.v;
}

// ---------------- fused MLP: h2 = (relu(agg@W1+b1))@W2 + b2, + BN stats ---
// 64 rows/block, grid 1563 (R11 geometry: 49.2 KB LDS, 3 blocks/CU).
// + R13: GEMM2 weight prefetch for kk=0,1 hoisted ahead of GEMM1 compute.
__global__ __launch_bounds__(256) void k_fused_mlp(
    _Float16* __restrict__ H2, const _Float16* __restrict__ A,
    const short* __restrict__ W1p, const float* __restrict__ b1,
    const short* __restrict__ W2p, const float* __restrict__ b2,
    float* __restrict__ stats)
{
    __shared__ __align__(16) char smem[49152];
    _Float16* As = (_Float16*)smem;              // [64][256] granule-XOR, 32 KB
    _Float16* Us = (_Float16*)(smem + 32768);    // [64][128] granule-XOR, 16 KB
    _Float16* Cs = (_Float16*)smem;              // epilogue [64][264] (overlay)

    const int t = threadIdx.x;
    const int w = t >> 6, lane = t & 63;
    const int quad = lane >> 4, l16 = lane & 15;
    const int bm = blockIdx.x;
    const int gm0 = bm * 64;
    const int swz = l16 & 7;

    // stage A tile (64x256 f16 = 32 KB), granule g of row r at slot g^(r&7)
#pragma unroll
    for (int i = 0; i < 8; ++i) {
        int u = i * 256 + t;            // 2048 granules
        int row = u >> 5;
        int gcol = (u & 31) ^ (row & 7);
        int grow = gm0 + row; if (grow > NN - 1) grow = NN - 1;
        async_load16(A + (size_t)grow * 256 + gcol * 8, (char*)As + u * 16);
    }

    f32x4 acc2[4][4];
#pragma unroll
    for (int i = 0; i < 4; ++i)
#pragma unroll
        for (int j = 0; j < 4; ++j) acc2[i][j] = (f32x4){0.f, 0.f, 0.f, 0.f};

    __syncthreads();

    for (int j = 0; j < 4; ++j) {
        // prefetch GEMM2 weights for kk=0,1 of this chunk (independent of Us;
        // stays in flight across GEMM1 compute + the barrier)
        half8 a2pre[2][4];
#pragma unroll
        for (int kk = 0; kk < 2; ++kk)
#pragma unroll
            for (int nt = 0; nt < 4; ++nt) {
                int n = w * 64 + nt * 16 + l16;
                a2pre[kk][nt] = *(const half8*)((const _Float16*)W2p +
                    ((size_t)(j * 4 + kk) * 256 + n) * 32 + quad * 8);
            }

        // ---- GEMM1 chunk: U^T (128 uc x 64 ur) = W1^T @ agg^T ----
        f32x4 acc1[2][4];
#pragma unroll
        for (int a = 0; a < 2; ++a)
#pragma unroll
            for (int b = 0; b < 4; ++b) acc1[a][b] = (f32x4){0.f, 0.f, 0.f, 0.f};

#pragma unroll
        for (int kb = 0; kb < 8; ++kb) {
            half8 a1[2], b1f[4];
#pragma unroll
            for (int ct = 0; ct < 2; ++ct) {
                int uc = j * 128 + w * 32 + ct * 16 + l16;
                a1[ct] = *(const half8*)((const _Float16*)W1p +
                         ((size_t)kb * 512 + uc) * 32 + quad * 8);
            }
            int slotA = (kb * 4 + quad) ^ swz;
#pragma unroll
            for (int urt = 0; urt < 4; ++urt)
                b1f[urt] = *(const half8*)(As + (urt * 16 + l16) * 256 + slotA * 8);
#pragma unroll
            for (int ct = 0; ct < 2; ++ct)
#pragma unroll
                for (int urt = 0; urt < 4; ++urt)
                    acc1[ct][urt] = __builtin_amdgcn_mfma_f32_16x16x32_f16(
                        a1[ct], b1f[urt], acc1[ct][urt], 0, 0, 0);
        }

        // write U chunk: relu(v+b1) -> f16, granule G of row ur at G^(ur&7)
#pragma unroll
        for (int ct = 0; ct < 2; ++ct) {
            int ucl = w * 32 + ct * 16 + quad * 4;
            float4 bv = *(const float4*)(b1 + j * 128 + ucl);
            int G = ucl >> 3;
            int hs = quad & 1;
#pragma unroll
            for (int urt = 0; urt < 4; ++urt) {
                int ur = urt * 16 + l16;
                int S = G ^ (ur & 7);
                half4v o;
                o[0] = (_Float16)fmaxf(acc1[ct][urt][0] + bv.x, 0.f);
                o[1] = (_Float16)fmaxf(acc1[ct][urt][1] + bv.y, 0.f);
                o[2] = (_Float16)fmaxf(acc1[ct][urt][2] + bv.z, 0.f);
                o[3] = (_Float16)fmaxf(acc1[ct][urt][3] + bv.w, 0.f);
                *(half4v*)(Us + ur * 128 + S * 8 + hs * 4) = o;
            }
        }
        __syncthreads();

        // ---- GEMM2 partial: h2^T += W2^T(k-chunk) @ U^T(chunk) ----
#pragma unroll
        for (int kk = 0; kk < 4; ++kk) {
            int kb2 = j * 4 + kk;
            half8 a2[4], b2f[4];
            if (kk < 2) {
#pragma unroll
                for (int nt = 0; nt < 4; ++nt) a2[nt] = a2pre[kk][nt];
            } else {
#pragma unroll
                for (int nt = 0; nt < 4; ++nt) {
                    int n = w * 64 + nt * 16 + l16;
                    a2[nt] = *(const half8*)((const _Float16*)W2p +
                             ((size_t)kb2 * 256 + n) * 32 + quad * 8);
                }
            }
            int slotU = (kk * 4 + quad) ^ swz;
#pragma unroll
            for (int mt = 0; mt < 4; ++mt)
                b2f[mt] = *(const half8*)(Us + (mt * 16 + l16) * 128 + slotU * 8);
#pragma unroll
            for (int nt = 0; nt < 4; ++nt)
#pragma unroll
                for (int mt = 0; mt < 4; ++mt)
                    acc2[nt][mt] = __builtin_amdgcn_mfma_f32_16x16x32_f16(
                        a2[nt], b2f[mt], acc2[nt][mt], 0, 0, 0);
        }
        __syncthreads();   // protect Us/As before next chunk
    }

    // ---- epilogue: bias + BN stats, coalesced store via LDS overlay ----
    int slot2 = bm & 63;
#pragma unroll
    for (int nt = 0; nt < 4; ++nt) {
        int nb = w * 64 + nt * 16 + quad * 4;
        float4 bv = *(const float4*)(b2 + nb);
        float s1[4] = {0.f, 0.f, 0.f, 0.f};
        float s2[4] = {0.f, 0.f, 0.f, 0.f};
#pragma unroll
        for (int mt = 0; mt < 4; ++mt) {
            int mr = mt * 16 + l16;
            int m = gm0 + mr;
            float v0 = acc2[nt][mt][0] + bv.x;
            float v1 = acc2[nt][mt][1] + bv.y;
            float v2 = acc2[nt][mt][2] + bv.z;
            float v3 = acc2[nt][mt][3] + bv.w;
            half4v o;
            o[0] = (_Float16)v0; o[1] = (_Float16)v1;
            o[2] = (_Float16)v2; o[3] = (_Float16)v3;
            *(half4v*)(Cs + mr * 264 + nb) = o;
            if (m < NN) {
                s1[0] += v0; s1[1] += v1; s1[2] += v2; s1[3] += v3;
                s2[0] += v0 * v0; s2[1] += v1 * v1;
                s2[2] += v2 * v2; s2[3] += v3 * v3;
            }
        }
#pragma unroll
        for (int r = 0; r < 4; ++r) {
            s1[r] += __shfl_xor(s1[r], 1, 64); s2[r] += __shfl_xor(s2[r], 1, 64);
            s1[r] += __shfl_xor(s1[r], 2, 64); s2[r] += __shfl_xor(s2[r], 2, 64);
            s1[r] += __shfl_xor(s1[r], 4, 64); s2[r] += __shfl_xor(s2[r], 4, 64);
            s1[r] += __shfl_xor(s1[r], 8, 64); s2[r] += __shfl_xor(s2[r], 8, 64);
            if (l16 == 0) {
                atomicAdd(&stats[slot2 * 512 + nb + r], s1[r]);
                atomicAdd(&stats[slot2 * 512 + 256 + nb + r], s2[r]);
            }
        }
    }
    __syncthreads();
#pragma unroll
    for (int i = 0; i < 8; ++i) {
        int u = i * 256 + t;
        int m = u >> 5, ch = u & 31;
        int grow = gm0 + m;
        if (grow < NN)
            *(int4*)(H2 + (size_t)grow * 256 + ch * 8) =
                *(const int4*)(Cs + m * 264 + ch * 8);
    }
}

// ---------------- BN finalize (+zero stats for next layer) ----------------
__global__ __launch_bounds__(256) void k_bn_finalize(
    float* __restrict__ scale, float* __restrict__ shift,
    float* __restrict__ stats,
    const float* __restrict__ bn_g, const float* __restrict__ bn_b)
{
    int t = threadIdx.x;
    float s1 = 0.f, s2 = 0.f;
    for (int j = 0; j < 64; ++j) {
        s1 += stats[j * 512 + t];
        s2 += stats[j * 512 + 256 + t];
        stats[j * 512 + t] = 0.f;
        stats[j * 512 + 256 + t] = 0.f;
    }
    float mu  = s1 / (float)NN;
    float var = s2 / (float)NN - mu * mu;
    float sc  = bn_g[t] * rsqrtf(var + 1e-5f);
    scale[t] = sc;
    shift[t] = bn_b[t] - mu * sc;
}

// ---------------- pool ----------------
__global__ __launch_bounds__(256) void k_pool(
    float* __restrict__ mol, const _Float16* __restrict__ h,
    const int* __restrict__ goffs,
    const float* __restrict__ scale, const float* __restrict__ shift)
{
    int g = blockIdx.x;
    int t = threadIdx.x;
    int s = goffs[g], e = goffs[g + 1];
    float sum = 0.f;
    for (int n = s; n < e; ++n) sum += (float)h[(size_t)n * 256 + t];
    int c = e - s; if (c < 1) c = 1;
    mol[(size_t)g * 256 + t] = fmaf(sum / (float)c, scale[t], shift[t]);
}

// ---------------- head MLP, 4 graphs/block, 1000 blocks ----------------
__global__ __launch_bounds__(256) void k_head(
    float* __restrict__ out, const float* __restrict__ mol,
    const float* __restrict__ hW0, const float* __restrict__ hb0,
    const float* __restrict__ hW1, const float* __restrict__ hb1,
    const float* __restrict__ hW2, const float* __restrict__ hb2,
    const float* __restrict__ hW3, const float* __restrict__ hb3,
    const float* __restrict__ hWo, const float* __restrict__ hbo)
{
    __shared__ float za[GPB][256];
    __shared__ float zb[GPB][256];
    const int t = threadIdx.x;
    const int g0 = blockIdx.x * GPB;

#pragma unroll
    for (int g = 0; g < GPB; ++g)
        za[g][t] = mol[(size_t)(g0 + g) * 256 + t];
    __syncthreads();

    {
        float acc[GPB];
#pragma unroll
        for (int g = 0; g < GPB; ++g) acc[g] = 0.f;
        for (int k = 0; k < 256; ++k) {
            float w = hW0[k * 256 + t];
#pragma unroll
            for (int g = 0; g < GPB; ++g) acc[g] = fmaf(za[g][k], w, acc[g]);
        }
        float b = hb0[t];
#pragma unroll
        for (int g = 0; g < GPB; ++g) zb[g][t] = fmaxf(acc[g] + b, 0.f);
    }
    __syncthreads();

    if (t < 128) {
        float acc[GPB];
#pragma unroll
        for (int g = 0; g < GPB; ++g) acc[g] = 0.f;
        for (int k = 0; k < 256; ++k) {
            float w = hW1[k * 128 + t];
#pragma unroll
            for (int g = 0; g < GPB; ++g) acc[g] = fmaf(zb[g][k], w, acc[g]);
        }
        float b = hb1[t];
#pragma unroll
        for (int g = 0; g < GPB; ++g) za[g][t] = fmaxf(acc[g] + b, 0.f);
    }
    __syncthreads();

    if (t < 64) {
        float acc[GPB];
#pragma unroll
        for (int g = 0; g < GPB; ++g) acc[g] = 0.f;
        for (int k = 0; k < 128; ++k) {
            float w = hW2[k * 64 + t];
#pragma unroll
            for (int g = 0; g < GPB; ++g) acc[g] = fmaf(za[g][k], w, acc[g]);
        }
        float b = hb2[t];
#pragma unroll
        for (int g = 0; g < GPB; ++g) zb[g][t] = fmaxf(acc[g] + b, 0.f);
    }
    __syncthreads();

    if (t < 32) {
        float acc[GPB];
#pragma unroll
        for (int g = 0; g < GPB; ++g) acc[g] = 0.f;
        for (int k = 0; k < 64; ++k) {
            float w = hW3[k * 32 + t];
#pragma unroll
            for (int g = 0; g < GPB; ++g) acc[g] = fmaf(zb[g][k], w, acc[g]);
        }
        float b = hb3[t];
#pragma unroll
        for (int g = 0; g < GPB; ++g) za[g][t] = fmaxf(acc[g] + b, 0.f);
    }
    __syncthreads();

    if (t < GPB) {
        float s = hbo[0];
        for (int k = 0; k < 32; ++k) s = fmaf(za[t][k], hWo[k], s);
        out[g0 + t] = s;
    }
}

extern "C" void kernel_launch(void* const* d_in, const int* in_sizes, int n_in,
                              void* d_out, int out_size, void* d_ws, size_t ws_size,
                              hipStream_t stream)
{
    const float* x    = (const float*)d_in[0];
    const int*   ei   = (const int*)d_in[1];
    const int*   ea   = (const int*)d_in[2];
    const int*   batch= (const int*)d_in[3];
    const float* embW = (const float*)d_in[4];
    const float* embB = (const float*)d_in[5];
    const float* ee1  = (const float*)d_in[6];
    const float* ee2  = (const float*)d_in[7];
    const float* W1   = (const float*)d_in[8];
    const float* b1   = (const float*)d_in[9];
    const float* W2   = (const float*)d_in[10];
    const float* b2   = (const float*)d_in[11];
    const float* bng  = (const float*)d_in[12];
    const float* bnb  = (const float*)d_in[13];
    const float* hW0  = (const float*)d_in[14];
    const float* hb0  = (const float*)d_in[15];
    const float* hW1  = (const float*)d_in[16];
    const float* hb1  = (const float*)d_in[17];
    const float* hW2  = (const float*)d_in[18];
    const float* hb2  = (const float*)d_in[19];
    const float* hW3  = (const float*)d_in[20];
    const float* hb3  = (const float*)d_in[21];
    const float* hWo  = (const float*)d_in[22];
    const float* hbo  = (const float*)d_in[23];
    float* out = (float*)d_out;

    char* ws = (char*)d_ws;
    size_t off = 0;
    _Float16* h2buf = (_Float16*)(ws + off); off += (size_t)NN * 256 * 2;
    _Float16* aggbuf= (_Float16*)(ws + off); off += (size_t)NN * 256 * 2;
    short* W1p      = (short*)(ws + off);    off += (size_t)5 * 131072 * 2;
    short* W2p      = (short*)(ws + off);    off += (size_t)5 * 131072 * 2;
    _Float16* Wep   = (_Float16*)(ws + off); off += (size_t)2 * 8192 * 2;
    float* tbl      = (float*)(ws + off);    off += (size_t)5 * 10 * 256 * 4;
    float* stats    = (float*)(ws + off);    off += (size_t)64 * 512 * 4;
    float* scale    = (float*)(ws + off);    off += 256 * 4;
    float* shift    = (float*)(ws + off);    off += 256 * 4;
    float* mol      = (float*)(ws + off);    off += (size_t)GG * 256 * 4;
    int* deg        = (int*)(ws + off);      off += (size_t)NN * 4;
    int* offs       = (int*)(ws + off);      off += (size_t)(NN + 1) * 4;
    int* cursor     = (int*)(ws + off);      off += (size_t)NN * 4;
    int* csr        = (int*)(ws + off);      off += (size_t)EE * 4;
    int* goffs      = (int*)(ws + off);      off += (size_t)(GG + 1) * 4;
    int* partial    = (int*)(ws + off);      off += 128 * 4;
    int* bases      = (int*)(ws + off);      off += 128 * 4;

    // ---- one-time per call ----
    hipMemsetAsync(deg, 0, (size_t)NN * 4, stream);
    hipMemsetAsync(stats, 0, (size_t)64 * 512 * 4, stream);
    k_count<<<(EE + 255) / 256, 256, 0, stream>>>(deg, ei);
    k_scan_partial<<<SC_NB, 256, 0, stream>>>(partial, deg);
    k_scan_base<<<1, 128, 0, stream>>>(bases, offs, partial);
    k_scan_final<<<SC_NB, 256, 0, stream>>>(offs, cursor, deg, bases);
    k_fill<<<(EE + 255) / 256, 256, 0, stream>>>(csr, cursor, ei, ea);
    k_goffs<<<(NN + 255) / 256, 256, 0, stream>>>(goffs, batch);
    k_combo<<<dim3(10, 5), 256, 0, stream>>>(tbl, ee1, ee2);
    k_pack<<<dim3(8, 8, 5), 256, 0, stream>>>(W1p, W1, 256, 512);
    k_pack<<<dim3(4, 16, 5), 256, 0, stream>>>(W2p, W2, 512, 256);
    k_pack_emb<<<64, 256, 0, stream>>>(Wep, embW);

    k_embed_mfma<<<782, 256, 0, stream>>>(h2buf, x, Wep, embB);

    const int FB = (NN + 63) / 64;   // 1563
    for (int l = 0; l < LL; ++l) {
        if (l == 0)
            k_aggregate<0><<<NN / 4, 256, 0, stream>>>(aggbuf, h2buf, offs, csr,
                                                       tbl, scale, shift);
        else
            k_aggregate<1><<<NN / 4, 256, 0, stream>>>(aggbuf, h2buf, offs, csr,
                                                       tbl + (size_t)l * 10 * 256, scale, shift);
        k_fused_mlp<<<FB, 256, 0, stream>>>(h2buf, aggbuf,
                                            W1p + (size_t)l * 131072, b1 + l * 512,
                                            W2p + (size_t)l * 131072, b2 + l * 256, stats);
        k_bn_finalize<<<1, 256, 0, stream>>>(scale, shift, stats, bng + l * 256, bnb + l * 256);
    }

    k_pool<<<GG, 256, 0, stream>>>(mol, h2buf, goffs, scale, shift);
    k_head<<<GG / GPB, 256, 0, stream>>>(out, mol,
                                         hW0, hb0, hW1, hb1, hW2, hb2, hW3, hb3, hWo, hbo);
}

// Round 14
// 1008.158 us; speedup vs baseline: 1.2688x; 1.2688x over previous
//
#include <hip/hip_runtime.h>
#include <hip/hip_bf16.h>

#define NN 100000
#define EE 300000
#define GG 4000
#define LL 5
#define GPB 4
#define SC_CHUNK 1024
#define SC_NB ((NN + SC_CHUNK - 1) / SC_CHUNK)   // 98

typedef _Float16 half8  __attribute__((ext_vector_type(8)));
typedef _Float16 half4v __attribute__((ext_vector_type(4)));
typedef float    f32x4  __attribute__((ext_vector_type(4)));

__device__ inline short f2h(float f) {
    _Float16 h = (_Float16)f;
    short s; __builtin_memcpy(&s, &h, 2); return s;
}

__device__ inline void async_load16(const void* g, void* l) {
    __builtin_amdgcn_global_load_lds(
        (const __attribute__((address_space(1))) unsigned int*)g,
        (__attribute__((address_space(3))) unsigned int*)l, 16, 0, 0);
}

// ---------------- CSR build ----------------
__global__ __launch_bounds__(256) void k_count(
    int* __restrict__ deg, const int* __restrict__ ei)
{
    int e = blockIdx.x * 256 + threadIdx.x;
    if (e < EE) atomicAdd(&deg[ei[EE + e]], 1);
}

__global__ __launch_bounds__(256) void k_scan_partial(
    int* __restrict__ partial, const int* __restrict__ deg)
{
    int b = blockIdx.x, t = threadIdx.x;
    int lane = t & 63, w = t >> 6;
    int base = b * SC_CHUNK + t * 4;
    int s = 0;
#pragma unroll
    for (int j = 0; j < 4; ++j) {
        int i = base + j;
        if (i < NN) s += deg[i];
    }
#pragma unroll
    for (int off = 1; off < 64; off <<= 1) s += __shfl_xor(s, off, 64);
    __shared__ int ws[4];
    if (lane == 0) ws[w] = s;
    __syncthreads();
    if (t == 0) partial[b] = ws[0] + ws[1] + ws[2] + ws[3];
}

__global__ __launch_bounds__(128) void k_scan_base(
    int* __restrict__ bases, int* __restrict__ offs, const int* __restrict__ partial)
{
    int t = threadIdx.x;
    int lane = t & 63, w = t >> 6;
    int p = (t < SC_NB) ? partial[t] : 0;
    int x = p;
#pragma unroll
    for (int off = 1; off < 64; off <<= 1) {
        int nb = __shfl_up(x, off, 64);
        if (lane >= off) x += nb;
    }
    __shared__ int w0tot;
    if (t == 63) w0tot = x;
    __syncthreads();
    if (w == 1) x += w0tot;
    if (t < SC_NB) bases[t] = x - p;
    if (t == 0) offs[NN] = EE;
}

__global__ __launch_bounds__(256) void k_scan_final(
    int* __restrict__ offs, int* __restrict__ cursor,
    const int* __restrict__ deg, const int* __restrict__ bases)
{
    int b = blockIdx.x, t = threadIdx.x;
    int lane = t & 63, w = t >> 6;
    int base = b * SC_CHUNK + t * 4;
    int v[4], pre[4], run = 0;
#pragma unroll
    for (int j = 0; j < 4; ++j) {
        int i = base + j;
        v[j] = (i < NN) ? deg[i] : 0;
        pre[j] = run;
        run += v[j];
    }
    int x = run;
#pragma unroll
    for (int off = 1; off < 64; off <<= 1) {
        int nb = __shfl_up(x, off, 64);
        if (lane >= off) x += nb;
    }
    int tex = x - run;
    __shared__ int ws[4];
    if (lane == 63) ws[w] = x;
    __syncthreads();
    int woff = 0;
    for (int k = 0; k < 4; ++k) if (k < w) woff += ws[k];
    int tbase = bases[b] + woff + tex;
#pragma unroll
    for (int j = 0; j < 4; ++j) {
        int i = base + j;
        if (i < NN) { offs[i] = tbase + pre[j]; cursor[i] = tbase + pre[j]; }
    }
}

__global__ __launch_bounds__(256) void k_fill(
    int* __restrict__ csr, int* __restrict__ cursor,
    const int* __restrict__ ei, const int* __restrict__ ea)
{
    int e = blockIdx.x * 256 + threadIdx.x;
    if (e >= EE) return;
    int s = ei[e];
    int d = ei[EE + e];
    int c = ea[2 * e] * 3 + ea[2 * e + 1];
    int slot = atomicAdd(&cursor[d], 1);
    csr[slot] = s | (c << 20);
}

// ---------------- graph offsets ----------------
__global__ __launch_bounds__(256) void k_goffs(
    int* __restrict__ goffs, const int* __restrict__ batch)
{
    int n = blockIdx.x * 256 + threadIdx.x;
    if (n >= NN) return;
    int b = batch[n];
    int bp = (n == 0) ? -1 : batch[n - 1];
    for (int g = bp + 1; g <= b; ++g) goffs[g] = n;
    if (n == NN - 1)
        for (int g = b + 1; g <= GG; ++g) goffs[g] = NN;
}

// ---------------- combo tables ----------------
__global__ __launch_bounds__(256) void k_combo(
    float* __restrict__ tbl, const float* __restrict__ ee1, const float* __restrict__ ee2)
{
    int c = blockIdx.x;
    int l = blockIdx.y;
    int t = threadIdx.x;
    int i1 = (c < 9) ? c / 3 : 4;
    int i2 = (c < 9) ? c % 3 : 0;
    tbl[((size_t)l * 10 + c) * 256 + t] =
        ee1[((size_t)l * 6 + i1) * 256 + t] + ee2[((size_t)l * 3 + i2) * 256 + t];
}

// ---------------- embW pack (fully parallel) ----------------
__global__ __launch_bounds__(256) void k_pack_emb(
    _Float16* __restrict__ Wep, const float* __restrict__ embW)
{
    int idx = blockIdx.x * 256 + threadIdx.x;   // 16384 total
    int ks = idx >> 13, r = idx & 8191;
    int n = r >> 5, kk = r & 31;
    int k = ks * 32 + kk;
    float v = (k < 40) ? embW[(size_t)k * 256 + n] : 0.f;
    Wep[idx] = (_Float16)v;
}

// ---------------- embed via MFMA ----------------
__global__ __launch_bounds__(256) void k_embed_mfma(
    _Float16* __restrict__ H, const float* __restrict__ x,
    const _Float16* __restrict__ Wep, const float* __restrict__ bias)
{
    __shared__ __align__(16) char smem[67584];
    _Float16* As = (_Float16*)smem;
    _Float16* Bs = (_Float16*)(smem + 16384);
    _Float16* Cs = (_Float16*)smem;

    const int t = threadIdx.x;
    const int w = t >> 6, lane = t & 63;
    const int quad = lane >> 4, l16 = lane & 15;
    const int wr = w >> 1, wc = w & 1;
    const int gm0 = blockIdx.x * 128;

#pragma unroll
    for (int i = 0; i < 8; ++i) {
        int u = i * 256 + t;
        async_load16((const char*)Wep + u * 16, (char*)Bs + u * 16);
    }

    {
        int row = t >> 1, half = t & 1;
        int rg = gm0 + row; if (rg > NN - 1) rg = NN - 1;
        const float* xp = x + (size_t)rg * 40 + half * 20;
        float v[20];
#pragma unroll
        for (int j = 0; j < 5; ++j) {
            float4 q = *(const float4*)(xp + j * 4);
            v[j * 4 + 0] = q.x; v[j * 4 + 1] = q.y; v[j * 4 + 2] = q.z; v[j * 4 + 3] = q.w;
        }
#pragma unroll
        for (int j = 0; j < 20; ++j) {
            int col = half * 20 + j;
            int ks = col >> 5, kk = col & 31;
            As[ks * 4096 + row * 32 + kk] = (_Float16)v[j];
        }
        int kb = 8 + half * 12;
#pragma unroll
        for (int j = 0; j < 12; ++j)
            As[4096 + row * 32 + kb + j] = (_Float16)0.f;
    }

    float biasreg[8];
#pragma unroll
    for (int nt = 0; nt < 8; ++nt)
        biasreg[nt] = bias[wc * 128 + nt * 16 + l16];

    f32x4 acc[4][8];
#pragma unroll
    for (int i = 0; i < 4; ++i)
#pragma unroll
        for (int j = 0; j < 8; ++j) acc[i][j] = (f32x4){0.f, 0.f, 0.f, 0.f};

    __syncthreads();

#pragma unroll
    for (int ks = 0; ks < 2; ++ks) {
        half8 af[4], bfr[8];
#pragma unroll
        for (int mt = 0; mt < 4; ++mt)
            af[mt] = *(const half8*)(As + ks * 4096 + (wr * 64 + mt * 16 + l16) * 32 + quad * 8);
#pragma unroll
        for (int nt = 0; nt < 8; ++nt)
            bfr[nt] = *(const half8*)(Bs + ks * 8192 + (wc * 128 + nt * 16 + l16) * 32 + quad * 8);
#pragma unroll
        for (int mt = 0; mt < 4; ++mt)
#pragma unroll
            for (int nt = 0; nt < 8; ++nt)
                acc[mt][nt] = __builtin_amdgcn_mfma_f32_16x16x32_f16(
                    af[mt], bfr[nt], acc[mt][nt], 0, 0, 0);
    }

    __syncthreads();
#pragma unroll
    for (int mt = 0; mt < 4; ++mt)
#pragma unroll
        for (int nt = 0; nt < 8; ++nt)
#pragma unroll
            for (int r = 0; r < 4; ++r) {
                int row = wr * 64 + mt * 16 + quad * 4 + r;
                int col = wc * 128 + nt * 16 + l16;
                Cs[row * 264 + col] = (_Float16)fmaxf(acc[mt][nt][r] + biasreg[nt], 0.f);
            }
    __syncthreads();
#pragma unroll
    for (int i = 0; i < 16; ++i) {
        int u = i * 256 + t;
        int m = u >> 5, ch = u & 31;
        int grow = gm0 + m;
        if (grow < NN)
            *(int4*)(H + (size_t)grow * 256 + ch * 8) =
                *(const int4*)(Cs + m * 264 + ch * 8);
    }
}

// ---------------- fused aggregate (AFF=0: identity affine, layer 0) -------
template <int AFF>
__global__ __launch_bounds__(256) void k_aggregate(
    _Float16* __restrict__ agg, const _Float16* __restrict__ hin,
    const int* __restrict__ offs, const int* __restrict__ csr,
    const float* __restrict__ tbl,
    const float* __restrict__ scale, const float* __restrict__ shift)
{
    int t = threadIdx.x;
    int w = t >> 6, lane = t & 63;
    int n = blockIdx.x * 4 + w;

    f32x4 sc, sh;
    if (AFF) { sc = ((const f32x4*)scale)[lane]; sh = ((const f32x4*)shift)[lane]; }
    const f32x4* tb4 = (const f32x4*)tbl;

    half4v hv = *(const half4v*)(hin + (size_t)n * 256 + lane * 4);
    f32x4 acc = tb4[9 * 64 + lane];
#pragma unroll
    for (int i = 0; i < 4; ++i) {
        float v = (float)hv[i];
        if (AFF) v = fmaf(v, sc[i], sh[i]);
        acc[i] += fmaxf(v, 0.f);
    }

    int o0 = offs[n], o1 = offs[n + 1];
    for (int j = o0; j < o1; ++j) {
        int entry = csr[j];
        int s = entry & 0xFFFFF;
        int c = entry >> 20;
        half4v gv = *(const half4v*)(hin + (size_t)s * 256 + lane * 4);
        f32x4 tv = tb4[c * 64 + lane];
#pragma unroll
        for (int i = 0; i < 4; ++i) {
            float v = (float)gv[i];
            if (AFF) v = fmaf(v, sc[i], sh[i]);
            acc[i] += fmaxf(v, 0.f) + tv[i];
        }
    }

    half4v o;
#pragma unroll
    for (int i = 0; i < 4; ++i) o[i] = (_Float16)acc[i];
    *(half4v*)(agg + (size_t)n * 256 + lane * 4) = o;
}

// ---------------- weight pack ----------------
__global__ __launch_bounds__(256) void k_pack(
    short* __restrict__ dst, const float* __restrict__ src, int K, int Nsz)
{
    int nb = blockIdx.x, kb = blockIdx.y, l = blockIdx.z;
    int t = threadIdx.x;
    __shared__ float T[32][65];
    const float* s = src + ((size_t)l * K + kb * 32) * Nsz + nb * 64;
#pragma unroll
    for (int i = 0; i < 8; ++i) {
        int idx = i * 256 + t;
        int kk = idx >> 6, nl = idx & 63;
        T[kk][nl] = s[(size_t)kk * Nsz + nl];
    }
    __syncthreads();
    int nl = t >> 2, kq = t & 3;
    union { short s[8]; int4 v; } o;
#pragma unroll
    for (int j = 0; j < 8; ++j) o.s[j] = f2h(T[kq * 8 + j][nl]);
    short* d = dst + (((size_t)l * (K / 32) + kb) * Nsz + nb * 64 + nl) * 32 + kq * 8;
    *(int4*)d = o.v;
}

// ---------------- fused MLP: h2 = (relu(agg@W1+b1))@W2 + b2, + BN stats ---
// 64 rows/block, grid 1563. Transposed MFMA: A-operands = packed weights
// from global (L2-hot), B-operands = activations in LDS. U lives only in
// LDS (XOR granule swizzle -> 2-way reads). Epilogue coalesced via LDS.
// NOTE (R12/R13): MB=96 (+LDS) and reg-prefetch (+VGPR) both cost occupancy
// (3 -> 2 blocks/CU) and regressed 50%+. This config is the local optimum.
__global__ __launch_bounds__(256) void k_fused_mlp(
    _Float16* __restrict__ H2, const _Float16* __restrict__ A,
    const short* __restrict__ W1p, const float* __restrict__ b1,
    const short* __restrict__ W2p, const float* __restrict__ b2,
    float* __restrict__ stats)
{
    __shared__ __align__(16) char smem[49152];
    _Float16* As = (_Float16*)smem;              // [64][256] granule-XOR, 32 KB
    _Float16* Us = (_Float16*)(smem + 32768);    // [64][128] granule-XOR, 16 KB
    _Float16* Cs = (_Float16*)smem;              // epilogue [64][264] (overlay)

    const int t = threadIdx.x;
    const int w = t >> 6, lane = t & 63;
    const int quad = lane >> 4, l16 = lane & 15;
    const int bm = blockIdx.x;
    const int gm0 = bm * 64;
    const int swz = l16 & 7;

    // stage A tile (64x256 f16 = 32 KB), granule g of row r at slot g^(r&7)
#pragma unroll
    for (int i = 0; i < 8; ++i) {
        int u = i * 256 + t;            // 2048 granules
        int row = u >> 5;
        int gcol = (u & 31) ^ (row & 7);
        int grow = gm0 + row; if (grow > NN - 1) grow = NN - 1;
        async_load16(A + (size_t)grow * 256 + gcol * 8, (char*)As + u * 16);
    }

    f32x4 acc2[4][4];
#pragma unroll
    for (int i = 0; i < 4; ++i)
#pragma unroll
        for (int j = 0; j < 4; ++j) acc2[i][j] = (f32x4){0.f, 0.f, 0.f, 0.f};

    __syncthreads();

    for (int j = 0; j < 4; ++j) {
        // ---- GEMM1 chunk: U^T (128 uc x 64 ur) = W1^T @ agg^T ----
        f32x4 acc1[2][4];
#pragma unroll
        for (int a = 0; a < 2; ++a)
#pragma unroll
            for (int b = 0; b < 4; ++b) acc1[a][b] = (f32x4){0.f, 0.f, 0.f, 0.f};

#pragma unroll
        for (int kb = 0; kb < 8; ++kb) {
            half8 a1[2], b1f[4];
#pragma unroll
            for (int ct = 0; ct < 2; ++ct) {
                int uc = j * 128 + w * 32 + ct * 16 + l16;
                a1[ct] = *(const half8*)((const _Float16*)W1p +
                         ((size_t)kb * 512 + uc) * 32 + quad * 8);
            }
            int slotA = (kb * 4 + quad) ^ swz;
#pragma unroll
            for (int urt = 0; urt < 4; ++urt)
                b1f[urt] = *(const half8*)(As + (urt * 16 + l16) * 256 + slotA * 8);
#pragma unroll
            for (int ct = 0; ct < 2; ++ct)
#pragma unroll
                for (int urt = 0; urt < 4; ++urt)
                    acc1[ct][urt] = __builtin_amdgcn_mfma_f32_16x16x32_f16(
                        a1[ct], b1f[urt], acc1[ct][urt], 0, 0, 0);
        }

        // write U chunk: relu(v+b1) -> f16, granule G of row ur at G^(ur&7)
#pragma unroll
        for (int ct = 0; ct < 2; ++ct) {
            int ucl = w * 32 + ct * 16 + quad * 4;
            float4 bv = *(const float4*)(b1 + j * 128 + ucl);
            int G = ucl >> 3;
            int hs = quad & 1;
#pragma unroll
            for (int urt = 0; urt < 4; ++urt) {
                int ur = urt * 16 + l16;
                int S = G ^ (ur & 7);
                half4v o;
                o[0] = (_Float16)fmaxf(acc1[ct][urt][0] + bv.x, 0.f);
                o[1] = (_Float16)fmaxf(acc1[ct][urt][1] + bv.y, 0.f);
                o[2] = (_Float16)fmaxf(acc1[ct][urt][2] + bv.z, 0.f);
                o[3] = (_Float16)fmaxf(acc1[ct][urt][3] + bv.w, 0.f);
                *(half4v*)(Us + ur * 128 + S * 8 + hs * 4) = o;
            }
        }
        __syncthreads();

        // ---- GEMM2 partial: h2^T += W2^T(k-chunk) @ U^T(chunk) ----
#pragma unroll
        for (int kk = 0; kk < 4; ++kk) {
            int kb2 = j * 4 + kk;
            half8 a2[4], b2f[4];
#pragma unroll
            for (int nt = 0; nt < 4; ++nt) {
                int n = w * 64 + nt * 16 + l16;
                a2[nt] = *(const half8*)((const _Float16*)W2p +
                         ((size_t)kb2 * 256 + n) * 32 + quad * 8);
            }
            int slotU = (kk * 4 + quad) ^ swz;
#pragma unroll
            for (int mt = 0; mt < 4; ++mt)
                b2f[mt] = *(const half8*)(Us + (mt * 16 + l16) * 128 + slotU * 8);
#pragma unroll
            for (int nt = 0; nt < 4; ++nt)
#pragma unroll
                for (int mt = 0; mt < 4; ++mt)
                    acc2[nt][mt] = __builtin_amdgcn_mfma_f32_16x16x32_f16(
                        a2[nt], b2f[mt], acc2[nt][mt], 0, 0, 0);
        }
        __syncthreads();   // protect Us/As before next chunk
    }

    // ---- epilogue: bias + BN stats, coalesced store via LDS overlay ----
    int slot2 = bm & 63;
#pragma unroll
    for (int nt = 0; nt < 4; ++nt) {
        int nb = w * 64 + nt * 16 + quad * 4;
        float4 bv = *(const float4*)(b2 + nb);
        float s1[4] = {0.f, 0.f, 0.f, 0.f};
        float s2[4] = {0.f, 0.f, 0.f, 0.f};
#pragma unroll
        for (int mt = 0; mt < 4; ++mt) {
            int mr = mt * 16 + l16;
            int m = gm0 + mr;
            float v0 = acc2[nt][mt][0] + bv.x;
            float v1 = acc2[nt][mt][1] + bv.y;
            float v2 = acc2[nt][mt][2] + bv.z;
            float v3 = acc2[nt][mt][3] + bv.w;
            half4v o;
            o[0] = (_Float16)v0; o[1] = (_Float16)v1;
            o[2] = (_Float16)v2; o[3] = (_Float16)v3;
            *(half4v*)(Cs + mr * 264 + nb) = o;
            if (m < NN) {
                s1[0] += v0; s1[1] += v1; s1[2] += v2; s1[3] += v3;
                s2[0] += v0 * v0; s2[1] += v1 * v1;
                s2[2] += v2 * v2; s2[3] += v3 * v3;
            }
        }
#pragma unroll
        for (int r = 0; r < 4; ++r) {
            s1[r] += __shfl_xor(s1[r], 1, 64); s2[r] += __shfl_xor(s2[r], 1, 64);
            s1[r] += __shfl_xor(s1[r], 2, 64); s2[r] += __shfl_xor(s2[r], 2, 64);
            s1[r] += __shfl_xor(s1[r], 4, 64); s2[r] += __shfl_xor(s2[r], 4, 64);
            s1[r] += __shfl_xor(s1[r], 8, 64); s2[r] += __shfl_xor(s2[r], 8, 64);
            if (l16 == 0) {
                atomicAdd(&stats[slot2 * 512 + nb + r], s1[r]);
                atomicAdd(&stats[slot2 * 512 + 256 + nb + r], s2[r]);
            }
        }
    }
    __syncthreads();
#pragma unroll
    for (int i = 0; i < 8; ++i) {
        int u = i * 256 + t;
        int m = u >> 5, ch = u & 31;
        int grow = gm0 + m;
        if (grow < NN)
            *(int4*)(H2 + (size_t)grow * 256 + ch * 8) =
                *(const int4*)(Cs + m * 264 + ch * 8);
    }
}

// ---------------- BN finalize (+zero stats for next layer) ----------------
__global__ __launch_bounds__(256) void k_bn_finalize(
    float* __restrict__ scale, float* __restrict__ shift,
    float* __restrict__ stats,
    const float* __restrict__ bn_g, const float* __restrict__ bn_b)
{
    int t = threadIdx.x;
    float s1 = 0.f, s2 = 0.f;
    for (int j = 0; j < 64; ++j) {
        s1 += stats[j * 512 + t];
        s2 += stats[j * 512 + 256 + t];
        stats[j * 512 + t] = 0.f;
        stats[j * 512 + 256 + t] = 0.f;
    }
    float mu  = s1 / (float)NN;
    float var = s2 / (float)NN - mu * mu;
    float sc  = bn_g[t] * rsqrtf(var + 1e-5f);
    scale[t] = sc;
    shift[t] = bn_b[t] - mu * sc;
}

// ---------------- pool ----------------
__global__ __launch_bounds__(256) void k_pool(
    float* __restrict__ mol, const _Float16* __restrict__ h,
    const int* __restrict__ goffs,
    const float* __restrict__ scale, const float* __restrict__ shift)
{
    int g = blockIdx.x;
    int t = threadIdx.x;
    int s = goffs[g], e = goffs[g + 1];
    float sum = 0.f;
    for (int n = s; n < e; ++n) sum += (float)h[(size_t)n * 256 + t];
    int c = e - s; if (c < 1) c = 1;
    mol[(size_t)g * 256 + t] = fmaf(sum / (float)c, scale[t], shift[t]);
}

// ---------------- head MLP, 4 graphs/block, 1000 blocks ----------------
__global__ __launch_bounds__(256) void k_head(
    float* __restrict__ out, const float* __restrict__ mol,
    const float* __restrict__ hW0, const float* __restrict__ hb0,
    const float* __restrict__ hW1, const float* __restrict__ hb1,
    const float* __restrict__ hW2, const float* __restrict__ hb2,
    const float* __restrict__ hW3, const float* __restrict__ hb3,
    const float* __restrict__ hWo, const float* __restrict__ hbo)
{
    __shared__ float za[GPB][256];
    __shared__ float zb[GPB][256];
    const int t = threadIdx.x;
    const int g0 = blockIdx.x * GPB;

#pragma unroll
    for (int g = 0; g < GPB; ++g)
        za[g][t] = mol[(size_t)(g0 + g) * 256 + t];
    __syncthreads();

    {
        float acc[GPB];
#pragma unroll
        for (int g = 0; g < GPB; ++g) acc[g] = 0.f;
        for (int k = 0; k < 256; ++k) {
            float w = hW0[k * 256 + t];
#pragma unroll
            for (int g = 0; g < GPB; ++g) acc[g] = fmaf(za[g][k], w, acc[g]);
        }
        float b = hb0[t];
#pragma unroll
        for (int g = 0; g < GPB; ++g) zb[g][t] = fmaxf(acc[g] + b, 0.f);
    }
    __syncthreads();

    if (t < 128) {
        float acc[GPB];
#pragma unroll
        for (int g = 0; g < GPB; ++g) acc[g] = 0.f;
        for (int k = 0; k < 256; ++k) {
            float w = hW1[k * 128 + t];
#pragma unroll
            for (int g = 0; g < GPB; ++g) acc[g] = fmaf(zb[g][k], w, acc[g]);
        }
        float b = hb1[t];
#pragma unroll
        for (int g = 0; g < GPB; ++g) za[g][t] = fmaxf(acc[g] + b, 0.f);
    }
    __syncthreads();

    if (t < 64) {
        float acc[GPB];
#pragma unroll
        for (int g = 0; g < GPB; ++g) acc[g] = 0.f;
        for (int k = 0; k < 128; ++k) {
            float w = hW2[k * 64 + t];
#pragma unroll
            for (int g = 0; g < GPB; ++g) acc[g] = fmaf(za[g][k], w, acc[g]);
        }
        float b = hb2[t];
#pragma unroll
        for (int g = 0; g < GPB; ++g) zb[g][t] = fmaxf(acc[g] + b, 0.f);
    }
    __syncthreads();

    if (t < 32) {
        float acc[GPB];
#pragma unroll
        for (int g = 0; g < GPB; ++g) acc[g] = 0.f;
        for (int k = 0; k < 64; ++k) {
            float w = hW3[k * 32 + t];
#pragma unroll
            for (int g = 0; g < GPB; ++g) acc[g] = fmaf(zb[g][k], w, acc[g]);
        }
        float b = hb3[t];
#pragma unroll
        for (int g = 0; g < GPB; ++g) za[g][t] = fmaxf(acc[g] + b, 0.f);
    }
    __syncthreads();

    if (t < GPB) {
        float s = hbo[0];
        for (int k = 0; k < 32; ++k) s = fmaf(za[t][k], hWo[k], s);
        out[g0 + t] = s;
    }
}

extern "C" void kernel_launch(void* const* d_in, const int* in_sizes, int n_in,
                              void* d_out, int out_size, void* d_ws, size_t ws_size,
                              hipStream_t stream)
{
    const float* x    = (const float*)d_in[0];
    const int*   ei   = (const int*)d_in[1];
    const int*   ea   = (const int*)d_in[2];
    const int*   batch= (const int*)d_in[3];
    const float* embW = (const float*)d_in[4];
    const float* embB = (const float*)d_in[5];
    const float* ee1  = (const float*)d_in[6];
    const float* ee2  = (const float*)d_in[7];
    const float* W1   = (const float*)d_in[8];
    const float* b1   = (const float*)d_in[9];
    const float* W2   = (const float*)d_in[10];
    const float* b2   = (const float*)d_in[11];
    const float* bng  = (const float*)d_in[12];
    const float* bnb  = (const float*)d_in[13];
    const float* hW0  = (const float*)d_in[14];
    const float* hb0  = (const float*)d_in[15];
    const float* hW1  = (const float*)d_in[16];
    const float* hb1  = (const float*)d_in[17];
    const float* hW2  = (const float*)d_in[18];
    const float* hb2  = (const float*)d_in[19];
    const float* hW3  = (const float*)d_in[20];
    const float* hb3  = (const float*)d_in[21];
    const float* hWo  = (const float*)d_in[22];
    const float* hbo  = (const float*)d_in[23];
    float* out = (float*)d_out;

    char* ws = (char*)d_ws;
    size_t off = 0;
    _Float16* h2buf = (_Float16*)(ws + off); off += (size_t)NN * 256 * 2;
    _Float16* aggbuf= (_Float16*)(ws + off); off += (size_t)NN * 256 * 2;
    short* W1p      = (short*)(ws + off);    off += (size_t)5 * 131072 * 2;
    short* W2p      = (short*)(ws + off);    off += (size_t)5 * 131072 * 2;
    _Float16* Wep   = (_Float16*)(ws + off); off += (size_t)2 * 8192 * 2;
    float* tbl      = (float*)(ws + off);    off += (size_t)5 * 10 * 256 * 4;
    float* stats    = (float*)(ws + off);    off += (size_t)64 * 512 * 4;
    float* scale    = (float*)(ws + off);    off += 256 * 4;
    float* shift    = (float*)(ws + off);    off += 256 * 4;
    float* mol      = (float*)(ws + off);    off += (size_t)GG * 256 * 4;
    int* deg        = (int*)(ws + off);      off += (size_t)NN * 4;
    int* offs       = (int*)(ws + off);      off += (size_t)(NN + 1) * 4;
    int* cursor     = (int*)(ws + off);      off += (size_t)NN * 4;
    int* csr        = (int*)(ws + off);      off += (size_t)EE * 4;
    int* goffs      = (int*)(ws + off);      off += (size_t)(GG + 1) * 4;
    int* partial    = (int*)(ws + off);      off += 128 * 4;
    int* bases      = (int*)(ws + off);      off += 128 * 4;

    // ---- one-time per call ----
    hipMemsetAsync(deg, 0, (size_t)NN * 4, stream);
    hipMemsetAsync(stats, 0, (size_t)64 * 512 * 4, stream);
    k_count<<<(EE + 255) / 256, 256, 0, stream>>>(deg, ei);
    k_scan_partial<<<SC_NB, 256, 0, stream>>>(partial, deg);
    k_scan_base<<<1, 128, 0, stream>>>(bases, offs, partial);
    k_scan_final<<<SC_NB, 256, 0, stream>>>(offs, cursor, deg, bases);
    k_fill<<<(EE + 255) / 256, 256, 0, stream>>>(csr, cursor, ei, ea);
    k_goffs<<<(NN + 255) / 256, 256, 0, stream>>>(goffs, batch);
    k_combo<<<dim3(10, 5), 256, 0, stream>>>(tbl, ee1, ee2);
    k_pack<<<dim3(8, 8, 5), 256, 0, stream>>>(W1p, W1, 256, 512);
    k_pack<<<dim3(4, 16, 5), 256, 0, stream>>>(W2p, W2, 512, 256);
    k_pack_emb<<<64, 256, 0, stream>>>(Wep, embW);

    k_embed_mfma<<<782, 256, 0, stream>>>(h2buf, x, Wep, embB);

    const int FB = (NN + 63) / 64;   // 1563
    for (int l = 0; l < LL; ++l) {
        if (l == 0)
            k_aggregate<0><<<NN / 4, 256, 0, stream>>>(aggbuf, h2buf, offs, csr,
                                                       tbl, scale, shift);
        else
            k_aggregate<1><<<NN / 4, 256, 0, stream>>>(aggbuf, h2buf, offs, csr,
                                                       tbl + (size_t)l * 10 * 256, scale, shift);
        k_fused_mlp<<<FB, 256, 0, stream>>>(h2buf, aggbuf,
                                            W1p + (size_t)l * 131072, b1 + l * 512,
                                            W2p + (size_t)l * 131072, b2 + l * 256, stats);
        k_bn_finalize<<<1, 256, 0, stream>>>(scale, shift, stats, bng + l * 256, bnb + l * 256);
    }

    k_pool<<<GG, 256, 0, stream>>>(mol, h2buf, goffs, scale, shift);
    k_head<<<GG / GPB, 256, 0, stream>>>(out, mol,
                                         hW0, hb0, hW1, hb1, hW2, hb2, hW3, hb3, hWo, hbo);
}